// Round 6
// baseline (1634.526 us; speedup 1.0000x reference)
//
#include <hip/hip_runtime.h>
#include <math.h>

#define D_MODEL 768
#define N_LAYER 8
#define D_STATE 128
#define D_CONV 4
#define HEADDIM 64
#define D_INNER 1536
#define NHEADS 24
#define D_IN_PROJ 3352   // 2*D_INNER + 2*D_STATE + NHEADS
#define CONV_DIM 1792    // D_INNER + 2*D_STATE
#define SEQLEN 1024
#define VOCAB 50288
#define EPS 1e-5f
#define T_SEG 32
#define NSEG  32         // SEQLEN / T_SEG

typedef __bf16 bf16x8 __attribute__((ext_vector_type(8)));
typedef float f32x4 __attribute__((ext_vector_type(4)));

__device__ inline unsigned short f2bf(float x) {
    union { float f; unsigned u; } v; v.f = x;
    unsigned r = v.u + 0x7fffu + ((v.u >> 16) & 1u);
    return (unsigned short)(r >> 16);
}
__device__ inline float bf2f(unsigned short b) {
    union { unsigned u; float f; } v; v.u = ((unsigned)b) << 16;
    return v.f;
}

// ---------------- embedding gather ----------------
__global__ void k_embed(const int* __restrict__ ids, const float* __restrict__ emb,
                        float* __restrict__ x) {
    int t = blockIdx.x;
    int id = ids[t];
    const float* er = emb + (long)id * D_MODEL;
    for (int d = threadIdx.x; d < D_MODEL; d += blockDim.x)
        x[(long)t * D_MODEL + d] = er[d];
}

// ---------------- LUT rmsnorm (768) -> fp32 + bf16 hi/lo; also zeroes mx ----------------
__global__ void k_lutnorm(const float* __restrict__ x, const float* __restrict__ w,
                          float* __restrict__ out, unsigned short* __restrict__ oh,
                          unsigned short* __restrict__ ol, unsigned* __restrict__ mx) {
    __shared__ float sbuf[256];
    int t = blockIdx.x;
    if (t == 0 && threadIdx.x == 0) *mx = 0u;
    const float* xr = x + (long)t * D_MODEL;
    float ss = 0.f;
    for (int d = threadIdx.x; d < D_MODEL; d += 256) { float v = xr[d]; ss += v * v; }
    sbuf[threadIdx.x] = ss; __syncthreads();
    for (int s = 128; s > 0; s >>= 1) {
        if (threadIdx.x < s) sbuf[threadIdx.x] += sbuf[threadIdx.x + s];
        __syncthreads();
    }
    float rms = sbuf[0] / (float)D_MODEL + EPS;
    const float X0 = 1e-5f;
    const float STEP = (10.0f - 1e-5f) / 255.0f;
    int idx = (int)ceilf((rms - X0) / STEP);
    idx = min(max(idx, 0), 255);
    while (idx > 0 && (X0 + (float)(idx - 1) * STEP) >= rms) --idx;
    while (idx < 255 && (X0 + (float)idx * STEP) < rms) ++idx;
    float scale = 1.0f / sqrtf(X0 + (float)idx * STEP);
    for (int d = threadIdx.x; d < D_MODEL; d += 256) {
        float v = xr[d] * scale * w[d];
        out[(long)t * D_MODEL + d] = v;
        unsigned short h = f2bf(v);
        oh[(long)t * D_MODEL + d] = h;
        ol[(long)t * D_MODEL + d] = f2bf(v - bf2f(h));
    }
}

// ---------------- fp32 -> bf16 (hi only) ----------------
__global__ void k_f2bf(const float* __restrict__ src, unsigned short* __restrict__ dst, int n8) {
    int i = blockIdx.x * 256 + threadIdx.x;
    int stride = gridDim.x * 256;
    for (; i < n8; i += stride) {
        const float* s = src + (size_t)i * 8;
        float4 a = *(const float4*)s, b = *(const float4*)(s + 4);
        float ff[8] = {a.x, a.y, a.z, a.w, b.x, b.y, b.z, b.w};
        unsigned short h[8];
#pragma unroll
        for (int j = 0; j < 8; ++j) h[j] = f2bf(ff[j]);
        uint4 u = make_uint4(h[0] | (h[1] << 16), h[2] | (h[3] << 16),
                             h[4] | (h[5] << 16), h[6] | (h[7] << 16));
        *(uint4*)(dst + (size_t)i * 8) = u;
    }
}

// ---------------- fp32 -> bf16 hi + lo ----------------
__global__ void k_f2bf2(const float* __restrict__ src, unsigned short* __restrict__ dh,
                        unsigned short* __restrict__ dl, int n8) {
    int i = blockIdx.x * 256 + threadIdx.x;
    int stride = gridDim.x * 256;
    for (; i < n8; i += stride) {
        const float* s = src + (size_t)i * 8;
        float4 a = *(const float4*)s, b = *(const float4*)(s + 4);
        float ff[8] = {a.x, a.y, a.z, a.w, b.x, b.y, b.z, b.w};
        unsigned short h[8], lo[8];
#pragma unroll
        for (int j = 0; j < 8; ++j) {
            h[j] = f2bf(ff[j]);
            lo[j] = f2bf(ff[j] - bf2f(h[j]));
        }
        uint4 uh = make_uint4(h[0] | (h[1] << 16), h[2] | (h[3] << 16),
                              h[4] | (h[5] << 16), h[6] | (h[7] << 16));
        uint4 ul = make_uint4(lo[0] | (lo[1] << 16), lo[2] | (lo[3] << 16),
                              lo[4] | (lo[5] << 16), lo[6] | (lo[7] << 16));
        *(uint4*)(dh + (size_t)i * 8) = uh;
        *(uint4*)(dl + (size_t)i * 8) = ul;
    }
}

// ======= MFMA GEMM, pre-converted bf16 operands, 128x128 tile, 512 thr, XCD swizzle =======
// C[M,N] = A[M,K]*B[N,K]^T, M=1024. PASSES=3: + Al*Bh + Ah*Bl. AMAX: absmax of C cols [1536,3328)
// Epilogue: LDS-bounce, 32-row chunks, float4 coalesced stores.
template <int PASSES, bool AMAX>
__global__ __launch_bounds__(512) void k_gemm_big(
    const unsigned short* __restrict__ Agh, const unsigned short* __restrict__ Agl,
    const unsigned short* __restrict__ Bgh, const unsigned short* __restrict__ Bgl,
    float* __restrict__ C, int N, int NT, int K, unsigned* __restrict__ mx) {
    const int i = blockIdx.x;
    const int rxcd = i & 7, xm = (i >> 3) & 7, q = i >> 6;
    const int y = q * 8 + rxcd;
    if (y >= NT) return;
    const int bm = xm * 128, bn = y * 128;

    constexpr int SMEM_BYTES = (PASSES == 3) ? 32768 : 16896;  // staging vs chunk-buf max
    __shared__ __align__(16) char smem[SMEM_BYTES];
    unsigned short (*Ah)[128][8] = (unsigned short(*)[128][8])(smem);
    unsigned short (*Bh)[128][8] = (unsigned short(*)[128][8])(smem + 8192);
    unsigned short (*Al)[128][8] = (unsigned short(*)[128][8])(smem + 16384);
    unsigned short (*Bl)[128][8] = (unsigned short(*)[128][8])(smem + 24576);

    const int tid = threadIdx.x;
    const int r = tid >> 2, g = tid & 3;       // staging: row 0..127, k-granule
    const int rsw = r ^ (g << 1);              // write-conflict XOR
    const int w = tid >> 6, l = tid & 63;
    const int wm = w >> 2, wn = w & 3;         // 2x4 waves: 64x32 out each
    const int lr = l & 15, lg = l >> 4;

    f32x4 acc[4][2];
#pragma unroll
    for (int m = 0; m < 4; ++m)
#pragma unroll
        for (int n = 0; n < 2; ++n) acc[m][n] = (f32x4){0.f, 0.f, 0.f, 0.f};

    for (int k0 = 0; k0 < K; k0 += 32) {
        {
            *(uint4*)&Ah[g][rsw][0] = *(const uint4*)(Agh + (size_t)(bm + r) * K + k0 + g * 8);
            if constexpr (PASSES == 3)
                *(uint4*)&Al[g][rsw][0] = *(const uint4*)(Agl + (size_t)(bm + r) * K + k0 + g * 8);
            int rB = bn + r;
            uint4 zb = make_uint4(0, 0, 0, 0);
            uint4 ubh = (rB < N) ? *(const uint4*)(Bgh + (size_t)rB * K + k0 + g * 8) : zb;
            *(uint4*)&Bh[g][rsw][0] = ubh;
            if constexpr (PASSES == 3) {
                uint4 ubl = (rB < N) ? *(const uint4*)(Bgl + (size_t)rB * K + k0 + g * 8) : zb;
                *(uint4*)&Bl[g][rsw][0] = ubl;
            }
        }
        __syncthreads();

        bf16x8 ah[4], al_[4], bh[2], bl_[2];
#pragma unroll
        for (int m = 0; m < 4; ++m) {
            int row = (wm * 64 + m * 16 + lr) ^ (lg << 1);
            ah[m] = *(const bf16x8*)&Ah[lg][row][0];
            if constexpr (PASSES == 3) al_[m] = *(const bf16x8*)&Al[lg][row][0];
        }
#pragma unroll
        for (int n = 0; n < 2; ++n) {
            int row = (wn * 32 + n * 16 + lr) ^ (lg << 1);
            bh[n] = *(const bf16x8*)&Bh[lg][row][0];
            if constexpr (PASSES == 3) bl_[n] = *(const bf16x8*)&Bl[lg][row][0];
        }
#pragma unroll
        for (int m = 0; m < 4; ++m)
#pragma unroll
            for (int n = 0; n < 2; ++n) {
                acc[m][n] = __builtin_amdgcn_mfma_f32_16x16x32_bf16(ah[m], bh[n], acc[m][n], 0, 0, 0);
                if constexpr (PASSES == 3) {
                    acc[m][n] = __builtin_amdgcn_mfma_f32_16x16x32_bf16(al_[m], bh[n], acc[m][n], 0, 0, 0);
                    acc[m][n] = __builtin_amdgcn_mfma_f32_16x16x32_bf16(ah[m], bl_[n], acc[m][n], 0, 0, 0);
                }
            }
        __syncthreads();
    }

    // absmax over conv-slice columns (from registers; same values as stored)
    if (AMAX) {
        float lmax = 0.f;
#pragma unroll
        for (int m = 0; m < 4; ++m)
#pragma unroll
            for (int n = 0; n < 2; ++n) {
                int col = bn + wn * 32 + n * 16 + lr;
                if (col >= D_INNER && col < D_INNER + CONV_DIM) {
#pragma unroll
                    for (int r4 = 0; r4 < 4; ++r4)
                        lmax = fmaxf(lmax, fabsf(acc[m][n][r4]));
                }
            }
#pragma unroll
        for (int s = 1; s <= 32; s <<= 1) lmax = fmaxf(lmax, __shfl_xor(lmax, s));
        if (l == 0) atomicMax(mx, __float_as_uint(lmax));
    }

    // LDS-bounce epilogue: 4 chunks of 32 rows, coalesced float4 stores
    float (*cbuf)[132] = (float(*)[132])smem;   // 32x132 fp32 = 16896 B, overlaps staging
    const int clrow = tid >> 4;                 // 0..31
    const int clcol = (tid & 15) * 8;           // 0..120
#pragma unroll
    for (int c = 0; c < 4; ++c) {
        if (c) __syncthreads();
        if (wm == (c >> 1)) {
#pragma unroll
            for (int mm = 0; mm < 2; ++mm) {
                int m = (c & 1) * 2 + mm;
                int lrow = mm * 16 + lg * 4;
#pragma unroll
                for (int n = 0; n < 2; ++n) {
                    int lcol = wn * 32 + n * 16 + lr;
#pragma unroll
                    for (int r4 = 0; r4 < 4; ++r4) cbuf[lrow + r4][lcol] = acc[m][n][r4];
                }
            }
        }
        __syncthreads();
        int grow = bm + c * 32 + clrow;
        int gcol = bn + clcol;
        float4 v0 = *(const float4*)&cbuf[clrow][clcol];
        float4 v1 = *(const float4*)&cbuf[clrow][clcol + 4];
        float* dst = C + (size_t)grow * N + gcol;
        if (gcol + 8 <= N) {
            *(float4*)dst = v0;
            *(float4*)(dst + 4) = v1;
        } else if (gcol < N) {
            float tmp[8] = {v0.x, v0.y, v0.z, v0.w, v1.x, v1.y, v1.z, v1.w};
            for (int j = 0; j < 8; ++j)
                if (gcol + j < N) dst[j] = tmp[j];
        }
    }
}

// ======= out_proj GEMM: 64x64 tile, 256 thr, PASSES=3, C += residual, XCD swizzle =======
__global__ __launch_bounds__(256) void k_gemm_out(
    const unsigned short* __restrict__ Agh, const unsigned short* __restrict__ Agl,
    const unsigned short* __restrict__ Bgh, const unsigned short* __restrict__ Bgl,
    float* __restrict__ C) {   // M=1024, N=768, K=1536
    const int K = 1536, N = 768;
    const int i = blockIdx.x;
    const int rxcd = i & 7, xm = (i >> 3) & 15, q = i >> 7;
    const int y = q * 8 + rxcd;
    if (y >= 12) return;
    const int bm = xm * 64, bn = y * 64;

    __shared__ __align__(16) char smem[16384];
    unsigned short (*Ah)[64][8] = (unsigned short(*)[64][8])(smem);
    unsigned short (*Bh)[64][8] = (unsigned short(*)[64][8])(smem + 4096);
    unsigned short (*Al)[64][8] = (unsigned short(*)[64][8])(smem + 8192);
    unsigned short (*Bl)[64][8] = (unsigned short(*)[64][8])(smem + 12288);

    const int tid = threadIdx.x;
    const int r = tid >> 2, g = tid & 3;
    const int rsw = r ^ (g << 1);
    const int w = tid >> 6, l = tid & 63;
    const int wm = w >> 1, wn = w & 1;        // 2x2 waves: 32x32 out each
    const int lr = l & 15, lg = l >> 4;

    f32x4 acc[2][2];
#pragma unroll
    for (int m = 0; m < 2; ++m)
#pragma unroll
        for (int n = 0; n < 2; ++n) acc[m][n] = (f32x4){0.f, 0.f, 0.f, 0.f};

    for (int k0 = 0; k0 < K; k0 += 32) {
        *(uint4*)&Ah[g][rsw][0] = *(const uint4*)(Agh + (size_t)(bm + r) * K + k0 + g * 8);
        *(uint4*)&Al[g][rsw][0] = *(const uint4*)(Agl + (size_t)(bm + r) * K + k0 + g * 8);
        *(uint4*)&Bh[g][rsw][0] = *(const uint4*)(Bgh + (size_t)(bn + r) * K + k0 + g * 8);
        *(uint4*)&Bl[g][rsw][0] = *(const uint4*)(Bgl + (size_t)(bn + r) * K + k0 + g * 8);
        __syncthreads();

        bf16x8 ah[2], al_[2], bh[2], bl_[2];
#pragma unroll
        for (int m = 0; m < 2; ++m) {
            int row = (wm * 32 + m * 16 + lr) ^ (lg << 1);
            ah[m] = *(const bf16x8*)&Ah[lg][row][0];
            al_[m] = *(const bf16x8*)&Al[lg][row][0];
        }
#pragma unroll
        for (int n = 0; n < 2; ++n) {
            int row = (wn * 32 + n * 16 + lr) ^ (lg << 1);
            bh[n] = *(const bf16x8*)&Bh[lg][row][0];
            bl_[n] = *(const bf16x8*)&Bl[lg][row][0];
        }
#pragma unroll
        for (int m = 0; m < 2; ++m)
#pragma unroll
            for (int n = 0; n < 2; ++n) {
                acc[m][n] = __builtin_amdgcn_mfma_f32_16x16x32_bf16(ah[m], bh[n], acc[m][n], 0, 0, 0);
                acc[m][n] = __builtin_amdgcn_mfma_f32_16x16x32_bf16(al_[m], bh[n], acc[m][n], 0, 0, 0);
                acc[m][n] = __builtin_amdgcn_mfma_f32_16x16x32_bf16(ah[m], bl_[n], acc[m][n], 0, 0, 0);
            }
        __syncthreads();
    }

    // LDS-bounce epilogue with residual add: 2 chunks of 32 rows
    float (*cbuf)[68] = (float(*)[68])smem;      // 32x68 fp32 = 8704 B
    const int clrow = tid >> 3;                  // 0..31
    const int clcol = (tid & 7) * 8;             // 0..56
#pragma unroll
    for (int c = 0; c < 2; ++c) {
        if (c) __syncthreads();
        if (wm == c) {
#pragma unroll
            for (int m = 0; m < 2; ++m) {
                int lrow = m * 16 + lg * 4;
#pragma unroll
                for (int n = 0; n < 2; ++n) {
                    int lcol = wn * 32 + n * 16 + lr;
#pragma unroll
                    for (int r4 = 0; r4 < 4; ++r4) cbuf[lrow + r4][lcol] = acc[m][n][r4];
                }
            }
        }
        __syncthreads();
        int grow = bm + c * 32 + clrow;
        float* dst = C + (size_t)grow * N + bn + clcol;
        float4 v0 = *(const float4*)&cbuf[clrow][clcol];
        float4 v1 = *(const float4*)&cbuf[clrow][clcol + 4];
        float4 r0 = *(const float4*)dst;
        float4 r1 = *(const float4*)(dst + 4);
        r0.x += v0.x; r0.y += v0.y; r0.z += v0.z; r0.w += v0.w;
        r1.x += v1.x; r1.y += v1.y; r1.z += v1.z; r1.w += v1.w;
        *(float4*)dst = r0;
        *(float4*)(dst + 4) = r1;
    }
}

// ---------------- fallback fp32-B GEMM (used only if ws too small) ----------------
template <int PASSES, bool ACCUM>
__global__ __launch_bounds__(256) void k_gemm_mfma(const float* __restrict__ A,
                                                   const float* __restrict__ B,
                                                   float* __restrict__ C,
                                                   int M, int N, int K) {
    __shared__ __align__(16) unsigned short Ah[4][128][8];
    __shared__ __align__(16) unsigned short Bh[4][128][8];
    __shared__ __align__(16) unsigned short Al[(PASSES == 3) ? 4 : 1][128][8];
    __shared__ __align__(16) unsigned short Bl[(PASSES == 3) ? 4 : 1][128][8];
    const int bm = blockIdx.x * 128, bn = blockIdx.y * 128;
    const int tid = threadIdx.x;
    const int rr = tid >> 2, g = tid & 3;
    const int w = tid >> 6, l = tid & 63;
    const int wm = w >> 1, wn = w & 1;
    const int lr = l & 15, lg = l >> 4;
    f32x4 acc[4][4];
#pragma unroll
    for (int m = 0; m < 4; ++m)
#pragma unroll
        for (int n = 0; n < 4; ++n) acc[m][n] = (f32x4){0.f, 0.f, 0.f, 0.f};
    for (int k0 = 0; k0 < K; k0 += 32) {
#pragma unroll
        for (int half = 0; half < 2; ++half) {
            int r = rr + half * 64;
            {
                const float* s = A + (size_t)(bm + r) * K + k0 + g * 8;
                float4 f0 = *(const float4*)s;
                float4 f1 = *(const float4*)(s + 4);
                float ff[8] = {f0.x, f0.y, f0.z, f0.w, f1.x, f1.y, f1.z, f1.w};
                unsigned short h[8], lo[8];
#pragma unroll
                for (int ii = 0; ii < 8; ++ii) {
                    h[ii] = f2bf(ff[ii]);
                    if (PASSES == 3) lo[ii] = f2bf(ff[ii] - bf2f(h[ii]));
                }
                *(uint4*)&Ah[g][r][0] = make_uint4(h[0] | (h[1] << 16), h[2] | (h[3] << 16),
                                                   h[4] | (h[5] << 16), h[6] | (h[7] << 16));
                if (PASSES == 3)
                    *(uint4*)&Al[g][r][0] = make_uint4(lo[0] | (lo[1] << 16), lo[2] | (lo[3] << 16),
                                                       lo[4] | (lo[5] << 16), lo[6] | (lo[7] << 16));
            }
            {
                int rB = bn + r;
                float ff[8] = {0.f, 0.f, 0.f, 0.f, 0.f, 0.f, 0.f, 0.f};
                if (rB < N) {
                    const float* s = B + (size_t)rB * K + k0 + g * 8;
                    float4 f0 = *(const float4*)s;
                    float4 f1 = *(const float4*)(s + 4);
                    ff[0] = f0.x; ff[1] = f0.y; ff[2] = f0.z; ff[3] = f0.w;
                    ff[4] = f1.x; ff[5] = f1.y; ff[6] = f1.z; ff[7] = f1.w;
                }
                unsigned short h[8], lo[8];
#pragma unroll
                for (int ii = 0; ii < 8; ++ii) {
                    h[ii] = f2bf(ff[ii]);
                    if (PASSES == 3) lo[ii] = f2bf(ff[ii] - bf2f(h[ii]));
                }
                *(uint4*)&Bh[g][r][0] = make_uint4(h[0] | (h[1] << 16), h[2] | (h[3] << 16),
                                                   h[4] | (h[5] << 16), h[6] | (h[7] << 16));
                if (PASSES == 3)
                    *(uint4*)&Bl[g][r][0] = make_uint4(lo[0] | (lo[1] << 16), lo[2] | (lo[3] << 16),
                                                       lo[4] | (lo[5] << 16), lo[6] | (lo[7] << 16));
            }
        }
        __syncthreads();
        bf16x8 ah[4], bh[4], al_[4], bl_[4];
#pragma unroll
        for (int m = 0; m < 4; ++m) {
            int row = wm * 64 + m * 16 + lr;
            ah[m] = *(const bf16x8*)&Ah[lg][row][0];
            if (PASSES == 3) al_[m] = *(const bf16x8*)&Al[lg][row][0];
        }
#pragma unroll
        for (int n = 0; n < 4; ++n) {
            int row = wn * 64 + n * 16 + lr;
            bh[n] = *(const bf16x8*)&Bh[lg][row][0];
            if (PASSES == 3) bl_[n] = *(const bf16x8*)&Bl[lg][row][0];
        }
#pragma unroll
        for (int m = 0; m < 4; ++m)
#pragma unroll
            for (int n = 0; n < 4; ++n) {
                acc[m][n] = __builtin_amdgcn_mfma_f32_16x16x32_bf16(ah[m], bh[n], acc[m][n], 0, 0, 0);
                if (PASSES == 3) {
                    acc[m][n] = __builtin_amdgcn_mfma_f32_16x16x32_bf16(al_[m], bh[n], acc[m][n], 0, 0, 0);
                    acc[m][n] = __builtin_amdgcn_mfma_f32_16x16x32_bf16(ah[m], bl_[n], acc[m][n], 0, 0, 0);
                }
            }
        __syncthreads();
    }
#pragma unroll
    for (int m = 0; m < 4; ++m) {
        int row0 = bm + wm * 64 + m * 16 + lg * 4;
#pragma unroll
        for (int n = 0; n < 4; ++n) {
            int col = bn + wn * 64 + n * 16 + lr;
            if (col < N) {
#pragma unroll
                for (int r4 = 0; r4 < 4; ++r4) {
                    size_t off = (size_t)(row0 + r4) * N + col;
                    if (ACCUM) C[off] += acc[m][n][r4]; else C[off] = acc[m][n][r4];
                }
            }
        }
    }
}

// ---------------- standalone absmax (fallback path only) ----------------
__global__ void k_absmax(const float* __restrict__ zx, unsigned* __restrict__ out) {
    __shared__ float sbuf[256];
    float m = 0.f;
    int total = SEQLEN * CONV_DIM;
    for (int i = blockIdx.x * blockDim.x + threadIdx.x; i < total; i += gridDim.x * blockDim.x) {
        int t = i / CONV_DIM, c = i - t * CONV_DIM;
        float v = fabsf(zx[(long)t * D_IN_PROJ + D_INNER + c]);
        m = fmaxf(m, v);
    }
    sbuf[threadIdx.x] = m; __syncthreads();
    for (int s = 128; s > 0; s >>= 1) {
        if (threadIdx.x < s) sbuf[threadIdx.x] = fmaxf(sbuf[threadIdx.x], sbuf[threadIdx.x + s]);
        __syncthreads();
    }
    if (threadIdx.x == 0) atomicMax(out, __float_as_uint(sbuf[0]));
}

// ---------------- fused quant + depthwise conv + silu ----------------
__global__ void k_convq(const float* __restrict__ zx, const float* __restrict__ qcw,
                        const float* __restrict__ cb, const float* __restrict__ cscale,
                        const unsigned* __restrict__ mx, float* __restrict__ xact) {
    int i = blockIdx.x * blockDim.x + threadIdx.x;
    if (i >= SEQLEN * CONV_DIM) return;
    float s = __uint_as_float(*mx) / (127.0f + 1e-8f);
    float inv_s = 1.0f / s;
    int t = i / CONV_DIM, c = i - t * CONV_DIM;
    float acc = cb[c];
#pragma unroll
    for (int k = 0; k < D_CONV; ++k) {
        int tt = t - (D_CONV - 1) + k;
        if (tt >= 0) {
            float q = rintf(zx[(size_t)tt * D_IN_PROJ + D_INNER + c] * inv_s);
            q = fminf(fmaxf(q, -128.0f), 127.0f);
            acc = fmaf(q, qcw[c * D_CONV + k], acc);
        }
    }
    float v = acc * (cscale[0] * s);
    xact[i] = v / (1.0f + expf(-v));
}

// ================= chunked SSM scan =================
__global__ __launch_bounds__(256) void k_scan_local(
    const float* __restrict__ xact, const float* __restrict__ zx,
    const float* __restrict__ dtbias, const float* __restrict__ A_log,
    float* __restrict__ y, float* __restrict__ hloc, float* __restrict__ dpre) {
    const int head = blockIdx.x;
    const int seg  = blockIdx.y;
    const int tid  = threadIdx.x;
    const int p  = tid >> 2;
    const int nc = tid & 3;
    const int t0 = seg * T_SEG;

    __shared__ float4 sB4[T_SEG][32];
    __shared__ float4 sC4[T_SEG][32];
    __shared__ float  sX[T_SEG][64];
    __shared__ float  sDt[T_SEG], sA[T_SEG];

#pragma unroll
    for (int it = 0; it < 4; ++it) {
        int slot = tid + it * 256;
        int t = slot >> 5, c4 = slot & 31;
        const float* rowp = xact + (size_t)(t0 + t) * CONV_DIM + D_INNER;
        float4 bv = *(const float4*)(rowp + c4 * 4);
        float4 cv = *(const float4*)(rowp + D_STATE + c4 * 4);
        int grp = c4 >> 3, r4 = c4 & 7;
        int sl = grp * 8 + ((r4 + 2 * grp) & 7);
        sB4[t][sl] = bv;
        sC4[t][sl] = cv;
    }
#pragma unroll
    for (int it = 0; it < 2; ++it) {
        int slot = tid + it * 256;
        int t = slot >> 4, c4 = slot & 15;
        *(float4*)&sX[t][c4 * 4] =
            *(const float4*)(xact + (size_t)(t0 + t) * CONV_DIM + head * HEADDIM + c4 * 4);
    }
    if (tid < T_SEG) {
        float v = zx[(size_t)(t0 + tid) * D_IN_PROJ + (D_INNER + CONV_DIM) + head] + dtbias[head];
        float dtv = fmaxf(v, 0.f) + log1pf(expf(-fabsf(v)));
        sDt[tid] = dtv;
        sA[tid] = expf(dtv * (-expf(A_log[head])));
    }
    __syncthreads();

    float h[32];
#pragma unroll
    for (int j = 0; j < 32; ++j) h[j] = 0.f;
    float d = 1.f;
    float* yrow = y + head * HEADDIM + p;

    for (int t = 0; t < T_SEG; ++t) {
        float a = sA[t], dtv = sDt[t];
        float xdt = sX[t][p] * dtv;
        d *= a;
        float acc = 0.f;
#pragma unroll
        for (int j4 = 0; j4 < 8; ++j4) {
            int sl = nc * 8 + ((j4 + 2 * nc) & 7);
            float4 Bv = sB4[t][sl];
            float4 Cv = sC4[t][sl];
            h[j4 * 4 + 0] = fmaf(a, h[j4 * 4 + 0], xdt * Bv.x); acc = fmaf(h[j4 * 4 + 0], Cv.x, acc);
            h[j4 * 4 + 1] = fmaf(a, h[j4 * 4 + 1], xdt * Bv.y); acc = fmaf(h[j4 * 4 + 1], Cv.y, acc);
            h[j4 * 4 + 2] = fmaf(a, h[j4 * 4 + 2], xdt * Bv.z); acc = fmaf(h[j4 * 4 + 2], Cv.z, acc);
            h[j4 * 4 + 3] = fmaf(a, h[j4 * 4 + 3], xdt * Bv.w); acc = fmaf(h[j4 * 4 + 3], Cv.w, acc);
        }
        acc += __shfl_xor(acc, 1);
        acc += __shfl_xor(acc, 2);
        if (nc == 0) yrow[(size_t)(t0 + t) * D_INNER] = acc;
        if (tid == 0) dpre[(head * NSEG + seg) * T_SEG + t] = d;
    }

    float* hb = hloc + ((size_t)(head * NSEG + seg) * 64 + p) * 128 + nc * 32;
#pragma unroll
    for (int j4 = 0; j4 < 8; ++j4)
        *(float4*)(hb + j4 * 4) =
            make_float4(h[j4 * 4], h[j4 * 4 + 1], h[j4 * 4 + 2], h[j4 * 4 + 3]);
}

__global__ __launch_bounds__(256) void k_scan_seg(float* __restrict__ hloc,
                                                  const float* __restrict__ dpre) {
    int g = blockIdx.x * 256 + threadIdx.x;
    int head = g >> 11;
    int e4 = g & 2047;
    float4 run = make_float4(0.f, 0.f, 0.f, 0.f);
    for (int seg = 0; seg < NSEG; ++seg) {
        float d = dpre[(head * NSEG + seg) * T_SEG + (T_SEG - 1)];
        float4* ptr = (float4*)hloc + (size_t)(head * NSEG + seg) * 2048 + e4;
        float4 v = *ptr;
        run.x = fmaf(d, run.x, v.x);
        run.y = fmaf(d, run.y, v.y);
        run.z = fmaf(d, run.z, v.z);
        run.w = fmaf(d, run.w, v.w);
        *ptr = run;
    }
}

__global__ __launch_bounds__(256) void k_scan_fix(
    const float* __restrict__ xact, const float* __restrict__ hloc,
    const float* __restrict__ dpre, float* __restrict__ y) {
    const int head = blockIdx.x;
    const int seg  = blockIdx.y + 1;
    const int tid  = threadIdx.x;
    const int p  = tid >> 2;
    const int nc = tid & 3;
    const int t0 = seg * T_SEG;

    __shared__ float4 sC4[T_SEG][32];
    __shared__ float  sD[T_SEG];

#pragma unroll
    for (int it = 0; it < 4; ++it) {
        int slot = tid + it * 256;
        int t = slot >> 5, c4 = slot & 31;
        float4 cv = *(const float4*)(xact + (size_t)(t0 + t) * CONV_DIM + D_INNER + D_STATE + c4 * 4);
        int grp = c4 >> 3, r4 = c4 & 7;
        sC4[t][grp * 8 + ((r4 + 2 * grp) & 7)] = cv;
    }
    if (tid < T_SEG) sD[tid] = dpre[(head * NSEG + seg) * T_SEG + tid];
    __syncthreads();

    float H[32];
    const float* hb = hloc + ((size_t)(head * NSEG + seg - 1) * 64 + p) * 128 + nc * 32;
#pragma unroll
    for (int j4 = 0; j4 < 8; ++j4) {
        float4 v = *(const float4*)(hb + j4 * 4);
        H[j4 * 4 + 0] = v.x; H[j4 * 4 + 1] = v.y; H[j4 * 4 + 2] = v.z; H[j4 * 4 + 3] = v.w;
    }
    float* yrow = y + head * HEADDIM + p;
    for (int t = 0; t < T_SEG; ++t) {
        float acc = 0.f;
#pragma unroll
        for (int j4 = 0; j4 < 8; ++j4) {
            int sl = nc * 8 + ((j4 + 2 * nc) & 7);
            float4 Cv = sC4[t][sl];
            acc = fmaf(H[j4 * 4 + 0], Cv.x, acc);
            acc = fmaf(H[j4 * 4 + 1], Cv.y, acc);
            acc = fmaf(H[j4 * 4 + 2], Cv.z, acc);
            acc = fmaf(H[j4 * 4 + 3], Cv.w, acc);
        }
        acc += __shfl_xor(acc, 1);
        acc += __shfl_xor(acc, 2);
        if (nc == 0) yrow[(size_t)(t0 + t) * D_INNER] += sD[t] * acc;
    }
}

// ---------------- gate + rmsnorm(1536) -> fp32 + bf16 hi/lo ----------------
__global__ void k_gatenorm(const float* __restrict__ ybuf, const float* __restrict__ zx,
                           const float* __restrict__ xact, const float* __restrict__ dpar,
                           const float* __restrict__ mnw, float* __restrict__ y3,
                           unsigned short* __restrict__ y3h, unsigned short* __restrict__ y3l) {
    __shared__ float sbuf[256];
    int t = blockIdx.x;
    const float* yr = ybuf + (long)t * D_INNER;
    const float* zr = zx + (long)t * D_IN_PROJ;
    const float* xa = xact + (long)t * CONV_DIM;
    float vals[6];
    float ss = 0.f;
#pragma unroll
    for (int j = 0; j < 6; ++j) {
        int e = threadIdx.x + j * 256;
        float z = zr[e];
        float v = (yr[e] + xa[e] * dpar[e >> 6]) * (z / (1.0f + expf(-z)));
        vals[j] = v; ss += v * v;
    }
    sbuf[threadIdx.x] = ss; __syncthreads();
    for (int s = 128; s > 0; s >>= 1) {
        if (threadIdx.x < s) sbuf[threadIdx.x] += sbuf[threadIdx.x + s];
        __syncthreads();
    }
    float scale = 1.0f / sqrtf(sbuf[0] / (float)D_INNER + EPS);
#pragma unroll
    for (int j = 0; j < 6; ++j) {
        int e = threadIdx.x + j * 256;
        float v = vals[j] * scale * mnw[e];
        y3[(long)t * D_INNER + e] = v;
        unsigned short h = f2bf(v);
        y3h[(long)t * D_INNER + e] = h;
        y3l[(long)t * D_INNER + e] = f2bf(v - bf2f(h));
    }
}

extern "C" void kernel_launch(void* const* d_in, const int* in_sizes, int n_in,
                              void* d_out, int out_size, void* d_ws, size_t ws_size,
                              hipStream_t stream) {
    const int*   ids    = (const int*)d_in[0];
    const float* emb    = (const float*)d_in[1];
    const float* norm_w = (const float*)d_in[2];
    const float* inw    = (const float*)d_in[3];
    const float* qconv  = (const float*)d_in[4];
    const float* cscale = (const float*)d_in[5];
    const float* convb  = (const float*)d_in[6];
    const float* dtbias = (const float*)d_in[7];
    const float* alog   = (const float*)d_in[8];
    const float* dpar   = (const float*)d_in[9];
    const float* mnw    = (const float*)d_in[10];
    const float* outw   = (const float*)d_in[11];
    const float* normf  = (const float*)d_in[12];
    const float* lmw    = (const float*)d_in[13];
    float* out = (float*)d_out;

    char* base = (char*)d_ws;
    size_t off = 0;
    auto alloc = [&](size_t bytes) { char* r = base + off; off = (off + bytes + 255) & ~(size_t)255; return r; };

    float* xres = (float*)alloc((size_t)SEQLEN * D_MODEL * 4);
    float* u    = (float*)alloc((size_t)SEQLEN * D_MODEL * 4);
    float* zx   = (float*)alloc((size_t)SEQLEN * D_IN_PROJ * 4);
    float* xact = (float*)alloc((size_t)SEQLEN * CONV_DIM * 4);
    float* ybuf = (float*)alloc((size_t)SEQLEN * D_INNER * 4);
    float* y3   = (float*)alloc((size_t)SEQLEN * D_INNER * 4);
    float* hloc = (float*)alloc((size_t)NHEADS * NSEG * HEADDIM * D_STATE * 4);
    float* dpre = (float*)alloc((size_t)NHEADS * NSEG * T_SEG * 4);
    unsigned* mx = (unsigned*)alloc(64);
    unsigned short* uh  = (unsigned short*)alloc((size_t)SEQLEN * D_MODEL * 2);
    unsigned short* ul  = (unsigned short*)alloc((size_t)SEQLEN * D_MODEL * 2);
    unsigned short* y3h = (unsigned short*)alloc((size_t)SEQLEN * D_INNER * 2);
    unsigned short* y3l = (unsigned short*)alloc((size_t)SEQLEN * D_INNER * 2);
    unsigned short* lmwh = (unsigned short*)alloc((size_t)VOCAB * D_MODEL * 2);
    size_t core_need = off;
    unsigned short* inwh = (unsigned short*)alloc((size_t)N_LAYER * D_IN_PROJ * D_MODEL * 2);
    unsigned short* inwl = (unsigned short*)alloc((size_t)N_LAYER * D_IN_PROJ * D_MODEL * 2);
    unsigned short* outwh = (unsigned short*)alloc((size_t)N_LAYER * D_MODEL * D_INNER * 2);
    unsigned short* outwl = (unsigned short*)alloc((size_t)N_LAYER * D_MODEL * D_INNER * 2);
    size_t full_need = off;
    const bool big = (ws_size >= full_need);
    (void)core_need;

    k_embed<<<SEQLEN, 256, 0, stream>>>(ids, emb, xres);
    k_f2bf<<<2048, 256, 0, stream>>>(lmw, lmwh, (VOCAB * D_MODEL) / 8);
    if (big) {
        k_f2bf2<<<2048, 256, 0, stream>>>(inw, inwh, inwl, (N_LAYER * D_IN_PROJ * D_MODEL) / 8);
        k_f2bf2<<<2048, 256, 0, stream>>>(outw, outwh, outwl, (N_LAYER * D_MODEL * D_INNER) / 8);
    }

    int nq = SEQLEN * CONV_DIM;
    const int NT_IN = (D_IN_PROJ + 127) / 128;    // 27
    const int NT_LM = (VOCAB + 127) / 128;        // 393
    for (int l = 0; l < N_LAYER; ++l) {
        k_lutnorm<<<SEQLEN, 256, 0, stream>>>(xres, norm_w + l * D_MODEL, u, uh, ul, mx);
        if (big) {
            int nblk = 8 * 8 * ((NT_IN + 7) / 8);
            k_gemm_big<3, true><<<nblk, 512, 0, stream>>>(
                uh, ul, inwh + (size_t)l * D_IN_PROJ * D_MODEL,
                inwl + (size_t)l * D_IN_PROJ * D_MODEL, zx, D_IN_PROJ, NT_IN, D_MODEL, mx);
        } else {
            dim3 g1(SEQLEN / 128, NT_IN);
            k_gemm_mfma<3, false><<<g1, 256, 0, stream>>>(u, inw + (size_t)l * D_IN_PROJ * D_MODEL,
                                                          zx, SEQLEN, D_IN_PROJ, D_MODEL);
            k_absmax<<<256, 256, 0, stream>>>(zx, mx);
        }
        k_convq<<<(nq + 255) / 256, 256, 0, stream>>>(zx, qconv + l * CONV_DIM * D_CONV,
                                                      convb + l * CONV_DIM, cscale + l, mx, xact);
        dim3 gs1(NHEADS, NSEG);
        k_scan_local<<<gs1, 256, 0, stream>>>(xact, zx, dtbias + l * NHEADS, alog + l * NHEADS,
                                              ybuf, hloc, dpre);
        k_scan_seg<<<192, 256, 0, stream>>>(hloc, dpre);
        dim3 gs3(NHEADS, NSEG - 1);
        k_scan_fix<<<gs3, 256, 0, stream>>>(xact, hloc, dpre, ybuf);
        k_gatenorm<<<SEQLEN, 256, 0, stream>>>(ybuf, zx, xact, dpar + l * NHEADS,
                                               mnw + l * D_INNER, y3, y3h, y3l);
        if (big) {
            k_gemm_out<<<256, 256, 0, stream>>>(y3h, y3l,
                outwh + (size_t)l * D_MODEL * D_INNER, outwl + (size_t)l * D_MODEL * D_INNER, xres);
        } else {
            dim3 g2(SEQLEN / 128, (D_MODEL + 127) / 128);
            k_gemm_mfma<3, true><<<g2, 256, 0, stream>>>(y3, outw + (size_t)l * D_MODEL * D_INNER,
                                                         xres, SEQLEN, D_MODEL, D_INNER);
        }
    }
    k_lutnorm<<<SEQLEN, 256, 0, stream>>>(xres, normf, u, uh, ul, mx);
    {
        int nblk = 8 * 8 * ((NT_LM + 7) / 8);
        k_gemm_big<1, false><<<nblk, 512, 0, stream>>>(uh, nullptr, lmwh, nullptr,
                                                       out, VOCAB, NT_LM, D_MODEL, nullptr);
    }
}